// Round 4
// baseline (560.877 us; speedup 1.0000x reference)
//
#include <hip/hip_runtime.h>

#define BB 4
#define NN 400
#define DD 100
#define SS 512

__device__ __forceinline__ float prelu_f(float v, float a) { return v >= 0.f ? v : a * v; }

// =====================================================================
// Generic register-tiled fp32 GEMM:  C[b] = A[b] (MxK, lda) @ B[b] (KxN)
// B source either row-major KxN (transB=0, ldb = row stride) or row-major
// NxK (transB=1, i.e. C[i,n] = sum_k A[i,k]*Bsrc[n*ldb+k]).
// Tile: BM=32, BN=128, KT=32. 256 threads, 4x4 micro-tile.
// Epilogues:
//  0: none
//  1: prelu(v + bias[n], *alpha)
//  2: v * rv[i]                      (row scale)
//  3: relu(rv[i]*v + bias[n])
//  4: prelu(v + bias[n], *alpha) + res[b*sRes + i*N + n]
//  5: (i==n) ? 1 : sqrt(max(rv[i]+rv[n]-2v, 0))   (pdist epilogue)
// =====================================================================
__global__ __launch_bounds__(256)
void mm100(const float* __restrict__ A, int lda, int sA,
           const float* __restrict__ Bsrc, int ldb, int sB, int transB,
           float* __restrict__ C, int sC, int M, int N, int K,
           int EP, const float* __restrict__ bias, const float* __restrict__ alpha,
           const float* __restrict__ rv, int rvStride,
           const float* __restrict__ res, int sRes)
{
    int b = blockIdx.z;
    const float* Ab = A + (size_t)b * sA;
    const float* Bb = Bsrc + (size_t)b * sB;
    float* Cb = C + (size_t)b * sC;
    int i0 = blockIdx.x * 32;
    int n0 = blockIdx.y * 128;
    int tid = threadIdx.x;
    int tx = tid & 31, ty = tid >> 5;

    __shared__ float sa[32][36];    // [k][row]  (padded, f4-aligned reads)
    __shared__ float sb[32][132];   // [k][col]

    float acc[4][4] = {{0.f}};

    for (int k0 = 0; k0 < K; k0 += 32) {
        // ---- stage A tile (32 rows x 32 k), transposed into sa[k][row]
        {
            int row = tid >> 3;
            int c4 = (tid & 7) * 4;
            float4 v = make_float4(0.f, 0.f, 0.f, 0.f);
            if (i0 + row < M && k0 + c4 < K)
                v = *(const float4*)&Ab[(size_t)(i0 + row) * lda + k0 + c4];
            sa[c4 + 0][row] = v.x;
            sa[c4 + 1][row] = v.y;
            sa[c4 + 2][row] = v.z;
            sa[c4 + 3][row] = v.w;
        }
        // ---- stage B tile (32 k x 128 n)
        if (!transB) {
#pragma unroll
            for (int it = 0; it < 4; ++it) {
                int idx = tid + it * 256;      // 1024 float4
                int kk = idx >> 5;
                int c4 = (idx & 31) * 4;
                float4 v = make_float4(0.f, 0.f, 0.f, 0.f);
                if (k0 + kk < K && n0 + c4 < N)
                    v = *(const float4*)&Bb[(size_t)(k0 + kk) * ldb + n0 + c4];
                *(float4*)&sb[kk][c4] = v;
            }
        } else {
#pragma unroll
            for (int it = 0; it < 4; ++it) {
                int idx = tid + it * 256;
                int n = idx >> 3;              // 0..127
                int c4 = (idx & 7) * 4;        // k chunk
                float4 v = make_float4(0.f, 0.f, 0.f, 0.f);
                if (n0 + n < N && k0 + c4 < K)
                    v = *(const float4*)&Bb[(size_t)(n0 + n) * ldb + k0 + c4];
                sb[c4 + 0][n] = v.x;
                sb[c4 + 1][n] = v.y;
                sb[c4 + 2][n] = v.z;
                sb[c4 + 3][n] = v.w;
            }
        }
        __syncthreads();
#pragma unroll 4
        for (int k = 0; k < 32; ++k) {
            float4 av = *(const float4*)&sa[k][ty * 4];
            float4 bv = *(const float4*)&sb[k][tx * 4];
            const float* ap = (const float*)&av;
            const float* bp = (const float*)&bv;
#pragma unroll
            for (int rr = 0; rr < 4; ++rr)
#pragma unroll
                for (int cc = 0; cc < 4; ++cc)
                    acc[rr][cc] = fmaf(ap[rr], bp[cc], acc[rr][cc]);
        }
        __syncthreads();
    }

    float al = alpha ? *alpha : 0.f;
    const float* rvb = rv ? rv + (size_t)b * rvStride : nullptr;
#pragma unroll
    for (int rr = 0; rr < 4; ++rr) {
        int i = i0 + ty * 4 + rr;
        if (i >= M) continue;
#pragma unroll
        for (int cc = 0; cc < 4; ++cc) {
            int n = n0 + tx * 4 + cc;
            if (n >= N) continue;
            float v = acc[rr][cc];
            if (EP == 1) v = prelu_f(v + bias[n], al);
            else if (EP == 2) v *= rvb[i];
            else if (EP == 3) { v = rvb[i] * v + bias[n]; v = v > 0.f ? v : 0.f; }
            else if (EP == 4) v = prelu_f(v + bias[n], al) + res[(size_t)b * sRes + (size_t)i * N + n];
            else if (EP == 5) {
                float d2 = rvb[i] + rvb[n] - 2.f * v;
                v = (i == n) ? 1.f : sqrtf(fmaxf(d2, 0.f));
            }
            Cb[(size_t)i * N + n] = v;
        }
    }
}

// =====================================================================
// Row softmax over 512 cols + sum(p^2).  block = one row (b*S+s), 512 thr
// =====================================================================
__global__ __launch_bounds__(512)
void k_softmax_sq(const float* __restrict__ scores, float* __restrict__ P,
                  float* __restrict__ sq)
{
    int row = blockIdx.x;
    int t = threadIdx.x;
    int w = t >> 6, lane = t & 63;
    __shared__ float sm[8];

    float v = scores[(size_t)row * SS + t];

    // block max
    float m = v;
    for (int off = 32; off; off >>= 1) m = fmaxf(m, __shfl_xor(m, off, 64));
    if (lane == 0) sm[w] = m;
    __syncthreads();
    m = sm[0];
#pragma unroll
    for (int i = 1; i < 8; ++i) m = fmaxf(m, sm[i]);
    __syncthreads();

    float e = expf(v - m);
    float s = e;
    for (int off = 32; off; off >>= 1) s += __shfl_xor(s, off, 64);
    if (lane == 0) sm[w] = s;
    __syncthreads();
    s = 0.f;
#pragma unroll
    for (int i = 0; i < 8; ++i) s += sm[i];
    __syncthreads();

    float p = e / s;
    P[(size_t)row * SS + t] = p;

    float q = p * p;
    for (int off = 32; off; off >>= 1) q += __shfl_xor(q, off, 64);
    if (lane == 0) sm[w] = q;
    __syncthreads();
    if (t == 0) {
        float r = 0.f;
#pragma unroll
        for (int i = 0; i < 8; ++i) r += sm[i];
        sq[row] = r;
    }
}

// =====================================================================
// dh[row] = rsqrt(rowsum(Bm))   block = row, 512 thr
// =====================================================================
__global__ __launch_bounds__(512)
void k_dh(const float* __restrict__ Bm, float* __restrict__ dh)
{
    int row = blockIdx.x;
    int t = threadIdx.x;
    int w = t >> 6, lane = t & 63;
    __shared__ float sm[8];
    float v = Bm[(size_t)row * SS + t];
    for (int off = 32; off; off >>= 1) v += __shfl_xor(v, off, 64);
    if (lane == 0) sm[w] = v;
    __syncthreads();
    if (t == 0) {
        float r = 0.f;
#pragma unroll
        for (int i = 0; i < 8; ++i) r += sm[i];
        dh[row] = rsqrtf(r);
    }
}

// =====================================================================
// Logits + softmax over n.  block = (b, 8 s-rows), 256 thr (4 waves).
// div written in (b, n, s) layout.
// =====================================================================
__global__ __launch_bounds__(256)
void k_div8(const float* __restrict__ h1, const float* __restrict__ h2,
            const float* __restrict__ b4a, const float* __restrict__ a4ap,
            const float* __restrict__ W4b, const float* __restrict__ b4bp,
            const float* __restrict__ a4bp, float* __restrict__ divT)
{
    int b = blockIdx.y;
    int s0 = blockIdx.x * 8;
    int tid = threadIdx.x;

    __shared__ float sh[8][104];   // h2 + b4a, padded
    __shared__ float sw[100];
    __shared__ float L[8][400];

    for (int idx = tid; idx < 800; idx += 256) {
        int s = idx / 100, d = idx - 100 * s;
        sh[s][d] = h2[((size_t)(b * SS + s0 + s)) * DD + d] + b4a[d];
    }
    if (tid < 100) sw[tid] = W4b[tid];
    __syncthreads();

    float a4a = *a4ap, a4b = *a4bp, b4b = *b4bp;

    for (int n = tid; n < NN; n += 256) {
        const float* h1r = &h1[((size_t)b * NN + n) * DD];
        float accs[8] = {0.f, 0.f, 0.f, 0.f, 0.f, 0.f, 0.f, 0.f};
        for (int j = 0; j < DD; j += 4) {
            float4 hv = *(const float4*)&h1r[j];
            float4 wv = *(const float4*)&sw[j];
#pragma unroll
            for (int s = 0; s < 8; ++s) {
                float4 cv = *(const float4*)&sh[s][j];
                float x0 = hv.x + cv.x; x0 = x0 > 0.f ? x0 : a4a * x0;
                float x1 = hv.y + cv.y; x1 = x1 > 0.f ? x1 : a4a * x1;
                float x2 = hv.z + cv.z; x2 = x2 > 0.f ? x2 : a4a * x2;
                float x3 = hv.w + cv.w; x3 = x3 > 0.f ? x3 : a4a * x3;
                accs[s] += x0 * wv.x + x1 * wv.y + x2 * wv.z + x3 * wv.w;
            }
        }
#pragma unroll
        for (int s = 0; s < 8; ++s) L[s][n] = prelu_f(accs[s] + b4b, a4b);
    }
    __syncthreads();

    int w = tid >> 6, lane = tid & 63;
    for (int si = w; si < 8; si += 4) {
        float m = -INFINITY;
        for (int n = lane; n < NN; n += 64) m = fmaxf(m, L[si][n]);
        for (int off = 32; off; off >>= 1) m = fmaxf(m, __shfl_xor(m, off, 64));
        float ss = 0.f;
        for (int n = lane; n < NN; n += 64) {
            float e = expf(L[si][n] - m);
            L[si][n] = e;
            ss += e;
        }
        for (int off = 32; off; off >>= 1) ss += __shfl_xor(ss, off, 64);
        float inv = 1.f / ss;
        for (int n = lane; n < NN; n += 64)
            divT[((size_t)b * NN + n) * SS + s0 + si] = L[si][n] * inv;
    }
}

extern "C" void kernel_launch(void* const* d_in, const int* in_sizes, int n_in,
                              void* d_out, int out_size, void* d_ws, size_t ws_size,
                              hipStream_t stream) {
    const float* x   = (const float*)d_in[0];
    const float* G   = (const float*)d_in[1];
    const float* Am  = (const float*)d_in[2];
    const float* Wgf = (const float*)d_in[3];
    const float* bgf = (const float*)d_in[4];
    const float* agf = (const float*)d_in[5];
    const float* Wg  = (const float*)d_in[6];
    const float* bg  = (const float*)d_in[7];
    const float* W4a = (const float*)d_in[8];
    const float* b4a = (const float*)d_in[9];
    const float* a4a = (const float*)d_in[10];
    const float* W4b = (const float*)d_in[11];
    const float* b4b = (const float*)d_in[12];
    const float* a4b = (const float*)d_in[13];
    const float* W5  = (const float*)d_in[14];
    const float* b5  = (const float*)d_in[15];
    const float* a5  = (const float*)d_in[16];
    float* out = (float*)d_out;

    float* ws  = (float*)d_ws;
    float* G1  = ws;                 // 51200
    float* Ax  = ws + 51200;         // 204800
    float* P   = ws + 256000;        // 1048576
    float* BmS = ws + 1304576;       // 1048576 (scores, then Bm)
    float* sq  = ws + 2353152;       // 2048
    float* dh  = ws + 2355200;       // 2048
    float* PW  = ws + 2357248;       // 204800
    float* T1s = ws + 2562048;       // 204800
    float* gx  = ws + 2766848;       // 204800
    float* h1  = ws + 2971648;       // 160000
    float* h2  = ws + 3131648;       // 204800
    float* tmp = ws + 3336448;       // 160000
    float* divT = P;                 // reuse P (dead after pw), 819200 <= 1048576

    // 1. G1 = prelu(G @ Wgf^T + bgf)           M=512 K=400 N=100, batch 1
    mm100<<<dim3(16, 1, 1), 256, 0, stream>>>(G, NN, 0, Wgf, NN, 0, 1,
        G1, 0, SS, DD, NN, 1, bgf, agf, nullptr, 0, nullptr, 0);
    // 2. Ax[b] = Amat @ x[b]                   M=512 K=400 N=100, batch 4
    mm100<<<dim3(16, 1, BB), 256, 0, stream>>>(Am, NN, 0, x, DD, NN * DD, 0,
        Ax, SS * DD, SS, DD, NN, 0, nullptr, nullptr, nullptr, 0, nullptr, 0);
    // 3. scores[b] = G1 @ Ax[b]^T              M=512 K=100 N=512, batch 4
    mm100<<<dim3(16, 4, BB), 256, 0, stream>>>(G1, DD, 0, Ax, DD, SS * DD, 1,
        BmS, SS * SS, SS, SS, DD, 0, nullptr, nullptr, nullptr, 0, nullptr, 0);
    // 4. P = softmax(scores), sq = sum(P^2)
    k_softmax_sq<<<BB * SS, 512, 0, stream>>>(BmS, P, sq);
    // 5. Bm = pdist epilogue on P @ P^T        M=N=K=512, batch 4
    mm100<<<dim3(16, 4, BB), 256, 0, stream>>>(P, SS, SS * SS, P, SS, SS * SS, 1,
        BmS, SS * SS, SS, SS, SS, 5, nullptr, nullptr, sq, SS, nullptr, 0);
    // 6. dh = rsqrt(rowsum(Bm))
    k_dh<<<BB * SS, 512, 0, stream>>>(BmS, dh);
    // 7. PW[b] = P[b] @ Wg^T                   M=512 K=512 N=100, batch 4
    mm100<<<dim3(16, 1, BB), 256, 0, stream>>>(P, SS, SS * SS, Wg, SS, 0, 1,
        PW, SS * DD, SS, DD, SS, 0, nullptr, nullptr, nullptr, 0, nullptr, 0);
    // 8. T1s[b] = diag(dh) @ (Bm @ PW)         M=512 K=512 N=100, batch 4
    mm100<<<dim3(16, 1, BB), 256, 0, stream>>>(BmS, SS, SS * SS, PW, DD, SS * DD, 0,
        T1s, SS * DD, SS, DD, SS, 2, nullptr, nullptr, dh, SS, nullptr, 0);
    // 9. gx[b] = relu(diag(dh) @ (Bm @ T1s) + bg)
    mm100<<<dim3(16, 1, BB), 256, 0, stream>>>(BmS, SS, SS * SS, T1s, DD, SS * DD, 0,
        gx, SS * DD, SS, DD, SS, 3, bg, nullptr, dh, SS, nullptr, 0);
    // 10. h1[b] = x[b] @ W4a[:, :100]^T        M=400 K=100 N=100
    mm100<<<dim3(13, 1, BB), 256, 0, stream>>>(x, DD, NN * DD, W4a, 2 * DD, 0, 1,
        h1, NN * DD, NN, DD, DD, 0, nullptr, nullptr, nullptr, 0, nullptr, 0);
    // 11. h2[b] = gx[b] @ W4a[:, 100:]^T       M=512 K=100 N=100
    mm100<<<dim3(16, 1, BB), 256, 0, stream>>>(gx, DD, SS * DD, W4a + DD, 2 * DD, 0, 1,
        h2, SS * DD, SS, DD, DD, 0, nullptr, nullptr, nullptr, 0, nullptr, 0);
    // 12. div (b,n,s) = softmax_n(logits)
    k_div8<<<dim3(SS / 8, BB), 256, 0, stream>>>(h1, h2, b4a, a4a, W4b, b4b, a4b, divT);
    // 13. tmp[b] = div[b] @ gx[b]              M=400 K=512 N=100
    mm100<<<dim3(13, 1, BB), 256, 0, stream>>>(divT, SS, NN * SS, gx, DD, SS * DD, 0,
        tmp, NN * DD, NN, DD, SS, 0, nullptr, nullptr, nullptr, 0, nullptr, 0);
    // 14. out = prelu(tmp @ W5^T + b5, a5) + x M=400 K=100 N=100
    mm100<<<dim3(13, 1, BB), 256, 0, stream>>>(tmp, DD, NN * DD, W5, DD, 0, 1,
        out, NN * DD, NN, DD, DD, 4, b5, a5, nullptr, 0, x, NN * DD);
}

// Round 5
// 347.877 us; speedup vs baseline: 1.6123x; 1.6123x over previous
//
#include <hip/hip_runtime.h>

#define BB 4
#define NN 400
#define DD 100
#define SS 512

__device__ __forceinline__ float prelu_f(float v, float a) { return v >= 0.f ? v : a * v; }

// =====================================================================
// Register-tiled fp32 GEMM, BM=16 x BN=128, KT=32, 128 threads, 4x4 micro.
// Register-prefetch double buffering (loads for tile t+1 issued before
// computing tile t).  Optional split-K: grid.z = batch*nsplit; block
// covers K range [split*kchunk, min(K, split*kchunk+kchunk)).
//   nsplit>1 : writes RAW partial to C[(b*nsplit+split)*M*N + i*N + n]
//   nsplit==1: applies epilogue EP and writes C[b*sC + i*N + n]
// Epilogues: 0 none | 4 prelu(v+bias[n],*alpha)+res | 5 pdist (symmetric,
// mirror-write, blocks with i0>n0+112 early-exit).
// =====================================================================
__global__ __launch_bounds__(128)
void mm16(const float* __restrict__ A, int lda, int sA,
          const float* __restrict__ Bsrc, int ldb, int sB, int transB,
          float* __restrict__ C, int sC, int M, int N, int K,
          int nsplit, int kchunk,
          int EP, const float* __restrict__ bias, const float* __restrict__ alpha,
          const float* __restrict__ rv, int rvStride,
          const float* __restrict__ res, int sRes)
{
    int zz = blockIdx.z;
    int b = zz / nsplit;
    int split = zz - b * nsplit;
    int kbeg = split * kchunk;
    int kend = min(K, kbeg + kchunk);

    int i0 = blockIdx.x * 16;
    int n0 = blockIdx.y * 128;
    if (EP == 5 && i0 > n0 + 112) return;   // symmetric output: lower part mirrored

    const float* Ab = A + (size_t)b * sA;
    const float* Bb = Bsrc + (size_t)b * sB;
    int tid = threadIdx.x;
    int tx = tid & 31, ty = tid >> 5;

    __shared__ float sa[32][20];    // [k][row]
    __shared__ float sb[32][132];   // [k][col]

    float4 pa;
    float4 pb[8];
    int arow = tid >> 3;            // 0..15
    int ac4  = (tid & 7) * 4;       // 0,4,..28

#define LOAD_TILE(KT)                                                         \
    {                                                                         \
        int kt_ = (KT);                                                       \
        pa = make_float4(0.f, 0.f, 0.f, 0.f);                                 \
        if (i0 + arow < M && kt_ + ac4 + 4 <= kend)                           \
            pa = *(const float4*)&Ab[(size_t)(i0 + arow) * lda + kt_ + ac4];  \
        if (!transB) {                                                        \
            _Pragma("unroll")                                                 \
            for (int it = 0; it < 8; ++it) {                                  \
                int idx = tid + it * 128;                                     \
                int kk = idx >> 5, c4 = (idx & 31) * 4;                       \
                float4 v = make_float4(0.f, 0.f, 0.f, 0.f);                   \
                if (kt_ + kk < kend && n0 + c4 + 4 <= N)                      \
                    v = *(const float4*)&Bb[(size_t)(kt_ + kk) * ldb + n0 + c4]; \
                pb[it] = v;                                                   \
            }                                                                 \
        } else {                                                              \
            _Pragma("unroll")                                                 \
            for (int it = 0; it < 8; ++it) {                                  \
                int idx = tid + it * 128;                                     \
                int n_ = idx >> 3, c4 = (idx & 7) * 4;                        \
                float4 v = make_float4(0.f, 0.f, 0.f, 0.f);                   \
                if (n0 + n_ < N && kt_ + c4 + 4 <= kend)                      \
                    v = *(const float4*)&Bb[(size_t)(n0 + n_) * ldb + kt_ + c4]; \
                pb[it] = v;                                                   \
            }                                                                 \
        }                                                                     \
    }

#define STORE_TILE()                                                          \
    {                                                                         \
        sa[ac4 + 0][arow] = pa.x;                                             \
        sa[ac4 + 1][arow] = pa.y;                                             \
        sa[ac4 + 2][arow] = pa.z;                                             \
        sa[ac4 + 3][arow] = pa.w;                                             \
        if (!transB) {                                                        \
            _Pragma("unroll")                                                 \
            for (int it = 0; it < 8; ++it) {                                  \
                int idx = tid + it * 128;                                     \
                int kk = idx >> 5, c4 = (idx & 31) * 4;                       \
                *(float4*)&sb[kk][c4] = pb[it];                               \
            }                                                                 \
        } else {                                                              \
            _Pragma("unroll")                                                 \
            for (int it = 0; it < 8; ++it) {                                  \
                int idx = tid + it * 128;                                     \
                int n_ = idx >> 3, c4 = (idx & 7) * 4;                        \
                sb[c4 + 0][n_] = pb[it].x;                                    \
                sb[c4 + 1][n_] = pb[it].y;                                    \
                sb[c4 + 2][n_] = pb[it].z;                                    \
                sb[c4 + 3][n_] = pb[it].w;                                    \
            }                                                                 \
        }                                                                     \
    }

    float acc[4][4] = {{0.f}};

    LOAD_TILE(kbeg);
    for (int kt = kbeg; kt < kend; kt += 32) {
        STORE_TILE();
        __syncthreads();
        if (kt + 32 < kend) LOAD_TILE(kt + 32);   // prefetch next tile (overlaps compute)
#pragma unroll
        for (int k = 0; k < 32; ++k) {
            float4 av = *(const float4*)&sa[k][ty * 4];
            float4 bv = *(const float4*)&sb[k][tx * 4];
            const float* ap = (const float*)&av;
            const float* bp = (const float*)&bv;
#pragma unroll
            for (int rr = 0; rr < 4; ++rr)
#pragma unroll
                for (int cc = 0; cc < 4; ++cc)
                    acc[rr][cc] = fmaf(ap[rr], bp[cc], acc[rr][cc]);
        }
        __syncthreads();
    }

    if (nsplit > 1) {
        float* Pp = C + (size_t)(b * nsplit + split) * M * N;
#pragma unroll
        for (int rr = 0; rr < 4; ++rr) {
            int i = i0 + ty * 4 + rr;
            if (i >= M) continue;
#pragma unroll
            for (int cc = 0; cc < 4; ++cc) {
                int n = n0 + tx * 4 + cc;
                if (n >= N) continue;
                Pp[(size_t)i * N + n] = acc[rr][cc];
            }
        }
        return;
    }

    float al = alpha ? *alpha : 0.f;
    const float* rvb = rv ? rv + (size_t)b * rvStride : nullptr;
    float* Cb = C + (size_t)b * sC;
#pragma unroll
    for (int rr = 0; rr < 4; ++rr) {
        int i = i0 + ty * 4 + rr;
        if (i >= M) continue;
#pragma unroll
        for (int cc = 0; cc < 4; ++cc) {
            int n = n0 + tx * 4 + cc;
            if (n >= N) continue;
            float v = acc[rr][cc];
            if (EP == 4) v = prelu_f(v + bias[n], al) + res[(size_t)b * sRes + (size_t)i * N + n];
            else if (EP == 5) {
                float d2 = rvb[i] + rvb[n] - 2.f * v;
                v = (i == n) ? 1.f : sqrtf(fmaxf(d2, 0.f));
            }
            Cb[(size_t)i * N + n] = v;
            if (EP == 5) Cb[(size_t)n * N + i] = v;   // mirror (identical value; diag band benign)
        }
    }
#undef LOAD_TILE
#undef STORE_TILE
}

// =====================================================================
// Split-K reduce with epilogue.  One float4 per thread.
// EP: 0 none | 1 prelu(v+bias[n],*alpha) | 2 v*rv[i] | 3 relu(rv[i]*v+bias[n])
// =====================================================================
__global__ __launch_bounds__(256)
void k_reduce(const float* __restrict__ part, int nsplit, float* __restrict__ C, int sC,
              int M, int N, int EP, const float* __restrict__ bias,
              const float* __restrict__ alpha, const float* __restrict__ rv, int rvStride)
{
    int b = blockIdx.y;
    int MN = M * N;
    int flat = (blockIdx.x * 256 + threadIdx.x) * 4;
    if (flat >= MN) return;
    const float* p = part + (size_t)b * nsplit * MN + flat;
    float4 v = *(const float4*)p;
    for (int s = 1; s < nsplit; ++s) {
        float4 w = *(const float4*)(p + (size_t)s * MN);
        v.x += w.x; v.y += w.y; v.z += w.z; v.w += w.w;
    }
    float o[4] = {v.x, v.y, v.z, v.w};
    int i = flat / N, n = flat - i * N;     // N % 4 == 0: float4 never crosses a row
    if (EP == 1) {
        float al = *alpha;
#pragma unroll
        for (int j = 0; j < 4; ++j) o[j] = prelu_f(o[j] + bias[n + j], al);
    } else if (EP == 2) {
        float r = rv[(size_t)b * rvStride + i];
#pragma unroll
        for (int j = 0; j < 4; ++j) o[j] *= r;
    } else if (EP == 3) {
        float r = rv[(size_t)b * rvStride + i];
#pragma unroll
        for (int j = 0; j < 4; ++j) { float t = r * o[j] + bias[n + j]; o[j] = t > 0.f ? t : 0.f; }
    }
    float* co = C + (size_t)b * sC + flat;
    *(float4*)co = make_float4(o[0], o[1], o[2], o[3]);
}

// =====================================================================
// Row softmax over 512 cols + sum(p^2).  block = one row, 512 thr
// =====================================================================
__global__ __launch_bounds__(512)
void k_softmax_sq(const float* __restrict__ scores, float* __restrict__ P,
                  float* __restrict__ sq)
{
    int row = blockIdx.x;
    int t = threadIdx.x;
    int w = t >> 6, lane = t & 63;
    __shared__ float sm[8];

    float v = scores[(size_t)row * SS + t];
    float m = v;
    for (int off = 32; off; off >>= 1) m = fmaxf(m, __shfl_xor(m, off, 64));
    if (lane == 0) sm[w] = m;
    __syncthreads();
    m = sm[0];
#pragma unroll
    for (int i = 1; i < 8; ++i) m = fmaxf(m, sm[i]);
    __syncthreads();

    float e = expf(v - m);
    float s = e;
    for (int off = 32; off; off >>= 1) s += __shfl_xor(s, off, 64);
    if (lane == 0) sm[w] = s;
    __syncthreads();
    s = 0.f;
#pragma unroll
    for (int i = 0; i < 8; ++i) s += sm[i];
    __syncthreads();

    float p = e / s;
    P[(size_t)row * SS + t] = p;

    float q = p * p;
    for (int off = 32; off; off >>= 1) q += __shfl_xor(q, off, 64);
    if (lane == 0) sm[w] = q;
    __syncthreads();
    if (t == 0) {
        float r = 0.f;
#pragma unroll
        for (int i = 0; i < 8; ++i) r += sm[i];
        sq[row] = r;
    }
}

// =====================================================================
// dh[row] = rsqrt(rowsum(Bm))
// =====================================================================
__global__ __launch_bounds__(512)
void k_dh(const float* __restrict__ Bm, float* __restrict__ dh)
{
    int row = blockIdx.x;
    int t = threadIdx.x;
    int w = t >> 6, lane = t & 63;
    __shared__ float sm[8];
    float v = Bm[(size_t)row * SS + t];
    for (int off = 32; off; off >>= 1) v += __shfl_xor(v, off, 64);
    if (lane == 0) sm[w] = v;
    __syncthreads();
    if (t == 0) {
        float r = 0.f;
#pragma unroll
        for (int i = 0; i < 8; ++i) r += sm[i];
        dh[row] = rsqrtf(r);
    }
}

// =====================================================================
// Logits + softmax over n.  block = (b, 8 s-rows), 256 thr.
// div written in (b, n, s) layout.
// =====================================================================
__global__ __launch_bounds__(256)
void k_div8(const float* __restrict__ h1, const float* __restrict__ h2,
            const float* __restrict__ b4a, const float* __restrict__ a4ap,
            const float* __restrict__ W4b, const float* __restrict__ b4bp,
            const float* __restrict__ a4bp, float* __restrict__ divT)
{
    int b = blockIdx.y;
    int s0 = blockIdx.x * 8;
    int tid = threadIdx.x;

    __shared__ float sh[8][104];
    __shared__ float sw[100];
    __shared__ float L[8][400];

    for (int idx = tid; idx < 800; idx += 256) {
        int s = idx / 100, d = idx - 100 * s;
        sh[s][d] = h2[((size_t)(b * SS + s0 + s)) * DD + d] + b4a[d];
    }
    if (tid < 100) sw[tid] = W4b[tid];
    __syncthreads();

    float a4a = *a4ap, a4b = *a4bp, b4b = *b4bp;

    for (int n = tid; n < NN; n += 256) {
        const float* h1r = &h1[((size_t)b * NN + n) * DD];
        float accs[8] = {0.f, 0.f, 0.f, 0.f, 0.f, 0.f, 0.f, 0.f};
        for (int j = 0; j < DD; j += 4) {
            float4 hv = *(const float4*)&h1r[j];
            float4 wv = *(const float4*)&sw[j];
#pragma unroll
            for (int s = 0; s < 8; ++s) {
                float4 cv = *(const float4*)&sh[s][j];
                float x0 = hv.x + cv.x; x0 = x0 > 0.f ? x0 : a4a * x0;
                float x1 = hv.y + cv.y; x1 = x1 > 0.f ? x1 : a4a * x1;
                float x2 = hv.z + cv.z; x2 = x2 > 0.f ? x2 : a4a * x2;
                float x3 = hv.w + cv.w; x3 = x3 > 0.f ? x3 : a4a * x3;
                accs[s] += x0 * wv.x + x1 * wv.y + x2 * wv.z + x3 * wv.w;
            }
        }
#pragma unroll
        for (int s = 0; s < 8; ++s) L[s][n] = prelu_f(accs[s] + b4b, a4b);
    }
    __syncthreads();

    int w = tid >> 6, lane = tid & 63;
    for (int si = w; si < 8; si += 4) {
        float m = -INFINITY;
        for (int n = lane; n < NN; n += 64) m = fmaxf(m, L[si][n]);
        for (int off = 32; off; off >>= 1) m = fmaxf(m, __shfl_xor(m, off, 64));
        float ss = 0.f;
        for (int n = lane; n < NN; n += 64) {
            float e = expf(L[si][n] - m);
            L[si][n] = e;
            ss += e;
        }
        for (int off = 32; off; off >>= 1) ss += __shfl_xor(ss, off, 64);
        float inv = 1.f / ss;
        for (int n = lane; n < NN; n += 64)
            divT[((size_t)b * NN + n) * SS + s0 + si] = L[si][n] * inv;
    }
}

extern "C" void kernel_launch(void* const* d_in, const int* in_sizes, int n_in,
                              void* d_out, int out_size, void* d_ws, size_t ws_size,
                              hipStream_t stream) {
    const float* x   = (const float*)d_in[0];
    const float* G   = (const float*)d_in[1];
    const float* Am  = (const float*)d_in[2];
    const float* Wgf = (const float*)d_in[3];
    const float* bgf = (const float*)d_in[4];
    const float* agf = (const float*)d_in[5];
    const float* Wg  = (const float*)d_in[6];
    const float* bg  = (const float*)d_in[7];
    const float* W4a = (const float*)d_in[8];
    const float* b4a = (const float*)d_in[9];
    const float* a4a = (const float*)d_in[10];
    const float* W4b = (const float*)d_in[11];
    const float* b4b = (const float*)d_in[12];
    const float* a4b = (const float*)d_in[13];
    const float* W5  = (const float*)d_in[14];
    const float* b5  = (const float*)d_in[15];
    const float* a5  = (const float*)d_in[16];
    float* out = (float*)d_out;

    float* ws  = (float*)d_ws;
    float* G1  = ws;                 // 51200
    float* Ax  = ws + 51200;         // 204800
    float* P   = ws + 256000;        // 1048576
    float* BmS = ws + 1304576;       // 1048576 (scores, then Bm)
    float* sq  = ws + 2353152;       // 2048
    float* dh  = ws + 2355200;       // 2048
    float* PW  = ws + 2357248;       // 204800
    float* T1s = ws + 2562048;       // 204800
    float* gx  = ws + 2766848;       // 204800
    float* h1  = ws + 2971648;       // 160000
    float* h2  = ws + 3131648;       // 204800
    float* tmp = ws + 3336448;       // 160000  (end 3496448)
    float* divT = P;                 // P dead after step 7; div written step 12
    float* part  = h1;               // split-K partials, steps 1-9 (h1/h2/tmp written later)
    float* partT = BmS;              // split-K partials, step 13 (BmS dead after step 9)

    // 1. G1 = prelu(G @ Wgf^T + bgf)            M=512 N=100 K=400, split-K 2
    mm16<<<dim3(32, 1, 2), 128, 0, stream>>>(G, NN, 0, Wgf, NN, 0, 1,
        part, 0, SS, DD, NN, 2, 224, 0, nullptr, nullptr, nullptr, 0, nullptr, 0);
    k_reduce<<<dim3(50, 1), 256, 0, stream>>>(part, 2, G1, SS * DD, SS, DD, 1, bgf, agf, nullptr, 0);
    // 2. Ax[b] = Amat @ x[b]                    M=512 N=100 K=400, split-K 2, b4
    mm16<<<dim3(32, 1, 8), 128, 0, stream>>>(Am, NN, 0, x, DD, NN * DD, 0,
        part, 0, SS, DD, NN, 2, 224, 0, nullptr, nullptr, nullptr, 0, nullptr, 0);
    k_reduce<<<dim3(50, BB), 256, 0, stream>>>(part, 2, Ax, SS * DD, SS, DD, 0, nullptr, nullptr, nullptr, 0);
    // 3. scores[b] = G1 @ Ax[b]^T               M=512 N=512 K=100
    mm16<<<dim3(32, 4, BB), 128, 0, stream>>>(G1, DD, 0, Ax, DD, SS * DD, 1,
        BmS, SS * SS, SS, SS, DD, 1, DD, 0, nullptr, nullptr, nullptr, 0, nullptr, 0);
    // 4. P = softmax(scores), sq = sum(P^2)
    k_softmax_sq<<<BB * SS, 512, 0, stream>>>(BmS, P, sq);
    // 5. Bm = pdist(P @ P^T), symmetric w/ mirror M=N=K=512
    mm16<<<dim3(32, 4, BB), 128, 0, stream>>>(P, SS, SS * SS, P, SS, SS * SS, 1,
        BmS, SS * SS, SS, SS, SS, 1, SS, 5, nullptr, nullptr, sq, SS, nullptr, 0);
    // 6. dh = rsqrt(rowsum(Bm))
    k_dh<<<BB * SS, 512, 0, stream>>>(BmS, dh);
    // 7. PW[b] = P[b] @ Wg^T                    M=512 N=100 K=512, split-K 2
    mm16<<<dim3(32, 1, 8), 128, 0, stream>>>(P, SS, SS * SS, Wg, SS, 0, 1,
        part, 0, SS, DD, SS, 2, 256, 0, nullptr, nullptr, nullptr, 0, nullptr, 0);
    k_reduce<<<dim3(50, BB), 256, 0, stream>>>(part, 2, PW, SS * DD, SS, DD, 0, nullptr, nullptr, nullptr, 0);
    // 8. T1s[b] = diag(dh) @ (Bm @ PW)          split-K 2
    mm16<<<dim3(32, 1, 8), 128, 0, stream>>>(BmS, SS, SS * SS, PW, DD, SS * DD, 0,
        part, 0, SS, DD, SS, 2, 256, 0, nullptr, nullptr, nullptr, 0, nullptr, 0);
    k_reduce<<<dim3(50, BB), 256, 0, stream>>>(part, 2, T1s, SS * DD, SS, DD, 2, nullptr, nullptr, dh, SS);
    // 9. gx[b] = relu(diag(dh) @ (Bm @ T1s) + bg) split-K 2
    mm16<<<dim3(32, 1, 8), 128, 0, stream>>>(BmS, SS, SS * SS, T1s, DD, SS * DD, 0,
        part, 0, SS, DD, SS, 2, 256, 0, nullptr, nullptr, nullptr, 0, nullptr, 0);
    k_reduce<<<dim3(50, BB), 256, 0, stream>>>(part, 2, gx, SS * DD, SS, DD, 3, bg, nullptr, dh, SS);
    // 10. h1[b] = x[b] @ W4a[:, :100]^T         M=400 N=100 K=100
    mm16<<<dim3(25, 1, BB), 128, 0, stream>>>(x, DD, NN * DD, W4a, 2 * DD, 0, 1,
        h1, NN * DD, NN, DD, DD, 1, DD, 0, nullptr, nullptr, nullptr, 0, nullptr, 0);
    // 11. h2[b] = gx[b] @ W4a[:, 100:]^T        M=512 N=100 K=100
    mm16<<<dim3(32, 1, BB), 128, 0, stream>>>(gx, DD, SS * DD, W4a + DD, 2 * DD, 0, 1,
        h2, SS * DD, SS, DD, DD, 1, DD, 0, nullptr, nullptr, nullptr, 0, nullptr, 0);
    // 12. div (b,n,s) = softmax_n(logits)
    k_div8<<<dim3(SS / 8, BB), 256, 0, stream>>>(h1, h2, b4a, a4a, W4b, b4b, a4b, divT);
    // 13. tmp[b] = div[b] @ gx[b]               M=400 N=100 K=512, split-K 2
    mm16<<<dim3(25, 1, 8), 128, 0, stream>>>(divT, SS, NN * SS, gx, DD, SS * DD, 0,
        partT, 0, NN, DD, SS, 2, 256, 0, nullptr, nullptr, nullptr, 0, nullptr, 0);
    k_reduce<<<dim3(40, BB), 256, 0, stream>>>(partT, 2, tmp, NN * DD, NN, DD, 0, nullptr, nullptr, nullptr, 0);
    // 14. out = prelu(tmp @ W5^T + b5, a5) + x  M=400 N=100 K=100
    mm16<<<dim3(25, 1, BB), 128, 0, stream>>>(tmp, DD, NN * DD, W5, DD, 0, 1,
        out, NN * DD, NN, DD, DD, 1, DD, 4, b5, a5, nullptr, 0, x, NN * DD);
}

// Round 6
// 343.110 us; speedup vs baseline: 1.6347x; 1.0139x over previous
//
#include <hip/hip_runtime.h>
#include <hip/hip_bf16.h>

#define BB 4
#define NN 400
#define DD 100
#define SS 512

typedef __attribute__((ext_vector_type(8))) short bf16x8;
typedef __attribute__((ext_vector_type(4))) float f32x4;

__device__ __forceinline__ float prelu_f(float v, float a) { return v >= 0.f ? v : a * v; }

__device__ __forceinline__ unsigned short f2bf(float x) {
    union { __hip_bfloat16 h; unsigned short u; } c;
    c.h = __float2bfloat16(x);   // RNE
    return c.u;
}
__device__ __forceinline__ float bf2f(unsigned short u) {
    return __uint_as_float(((unsigned)u) << 16);
}

__device__ __forceinline__ bf16x8 ldfrag(const unsigned short* rowp, int grp) {
    ushort4 lo = *(const ushort4*)(rowp + grp * 4);
    ushort4 hi = *(const ushort4*)(rowp + grp * 4 + 16);
    bf16x8 r = {(short)lo.x, (short)lo.y, (short)lo.z, (short)lo.w,
                (short)hi.x, (short)hi.y, (short)hi.z, (short)hi.w};
    return r;
}

// =====================================================================
// MFMA bf16 GEMM: C = A (MxK fp32, lda) @ op(B).  1 wave, 32x32 tile,
// K-tile 32.  fp32 operands are converted to bf16 (RNE) at LDS staging.
// transB=1: B is [n][k] row-major (ldb=k-stride); transB=0: B is [k][n].
// nsplit>1: raw partials to C[(b*nsplit+split)*M*N + i*N + n]  (k_reduce
// applies the epilogue).  nsplit==1: EP 0 none | 4 prelu(v+bias[n],*alpha)
// +res | 5 pdist (needs rv=sq; triangular: blocks i0>n0 skipped, mirror
// writes fill the lower half).
// =====================================================================
__global__ __launch_bounds__(64)
void mmfa(const float* __restrict__ A, int lda, int sA,
          const float* __restrict__ B, int ldb, int sB, int transB,
          float* __restrict__ C, int sC, int M, int N, int K,
          int nsplit, int kchunk, int EP,
          const float* __restrict__ bias, const float* __restrict__ alpha,
          const float* __restrict__ rv, int rvStride,
          const float* __restrict__ res, int sRes)
{
    int zz = blockIdx.z;
    int b = zz / nsplit, split = zz - b * nsplit;
    int kbeg = split * kchunk, kend = min(K, kbeg + kchunk);
    int i0 = blockIdx.x * 32, n0 = blockIdx.y * 32;
    if (EP == 5 && i0 > n0) return;          // symmetric: lower mirrored

    const float* Ab = A + (size_t)b * sA;
    const float* Bb = B + (size_t)b * sB;
    int lane = threadIdx.x;
    int r16 = lane & 15, grp = lane >> 4;

    __shared__ unsigned short sa[32][36];    // [m][k] bf16, padded
    __shared__ unsigned short sb[32][36];    // [n][k] bf16, padded

    f32x4 acc[2][2];
#pragma unroll
    for (int fm = 0; fm < 2; ++fm)
#pragma unroll
        for (int fn = 0; fn < 2; ++fn)
            acc[fm][fn] = (f32x4){0.f, 0.f, 0.f, 0.f};

    for (int kt = kbeg; kt < kend; kt += 32) {
        // ---- stage A (32 rows x 32 k), fp32 -> bf16
#pragma unroll
        for (int it = 0; it < 4; ++it) {
            int idx = lane + it * 64;
            int m = idx >> 3, kq = (idx & 7) * 4;
            float4 v = make_float4(0.f, 0.f, 0.f, 0.f);
            if (i0 + m < M && kt + kq + 4 <= kend)
                v = *(const float4*)&Ab[(size_t)(i0 + m) * lda + kt + kq];
            ushort4 u;
            u.x = f2bf(v.x); u.y = f2bf(v.y); u.z = f2bf(v.z); u.w = f2bf(v.w);
            *(ushort4*)&sa[m][kq] = u;
        }
        // ---- stage B
        if (transB) {
#pragma unroll
            for (int it = 0; it < 4; ++it) {
                int idx = lane + it * 64;
                int n_ = idx >> 3, kq = (idx & 7) * 4;
                float4 v = make_float4(0.f, 0.f, 0.f, 0.f);
                if (n0 + n_ < N && kt + kq + 4 <= kend)
                    v = *(const float4*)&Bb[(size_t)(n0 + n_) * ldb + kt + kq];
                ushort4 u;
                u.x = f2bf(v.x); u.y = f2bf(v.y); u.z = f2bf(v.z); u.w = f2bf(v.w);
                *(ushort4*)&sb[n_][kq] = u;
            }
        } else {
#pragma unroll
            for (int it = 0; it < 4; ++it) {
                int idx = lane + it * 64;
                int kk = idx >> 3, nq = (idx & 7) * 4;
                float4 v = make_float4(0.f, 0.f, 0.f, 0.f);
                if (kt + kk < kend && n0 + nq + 4 <= N)
                    v = *(const float4*)&Bb[(size_t)(kt + kk) * ldb + n0 + nq];
                sb[nq + 0][kk] = f2bf(v.x);
                sb[nq + 1][kk] = f2bf(v.y);
                sb[nq + 2][kk] = f2bf(v.z);
                sb[nq + 3][kk] = f2bf(v.w);
            }
        }
        __syncthreads();

        bf16x8 a0 = ldfrag(&sa[r16][0], grp);
        bf16x8 a1 = ldfrag(&sa[16 + r16][0], grp);
        bf16x8 b0 = ldfrag(&sb[r16][0], grp);
        bf16x8 b1 = ldfrag(&sb[16 + r16][0], grp);
        acc[0][0] = __builtin_amdgcn_mfma_f32_16x16x32_bf16(a0, b0, acc[0][0], 0, 0, 0);
        acc[0][1] = __builtin_amdgcn_mfma_f32_16x16x32_bf16(a0, b1, acc[0][1], 0, 0, 0);
        acc[1][0] = __builtin_amdgcn_mfma_f32_16x16x32_bf16(a1, b0, acc[1][0], 0, 0, 0);
        acc[1][1] = __builtin_amdgcn_mfma_f32_16x16x32_bf16(a1, b1, acc[1][1], 0, 0, 0);
        __syncthreads();
    }

    // ---- store: C row = i0 + fm*16 + grp*4 + reg, col = n0 + fn*16 + r16
    if (nsplit > 1) {
        float* Pp = C + (size_t)(b * nsplit + split) * M * N;
#pragma unroll
        for (int fm = 0; fm < 2; ++fm)
#pragma unroll
            for (int fn = 0; fn < 2; ++fn)
#pragma unroll
                for (int reg = 0; reg < 4; ++reg) {
                    int i = i0 + fm * 16 + grp * 4 + reg;
                    int n = n0 + fn * 16 + r16;
                    if (i < M && n < N) Pp[(size_t)i * N + n] = acc[fm][fn][reg];
                }
        return;
    }

    float al = alpha ? *alpha : 0.f;
    const float* rvb = rv ? rv + (size_t)b * rvStride : nullptr;
    float* Cb = C + (size_t)b * sC;
#pragma unroll
    for (int fm = 0; fm < 2; ++fm)
#pragma unroll
        for (int fn = 0; fn < 2; ++fn)
#pragma unroll
            for (int reg = 0; reg < 4; ++reg) {
                int i = i0 + fm * 16 + grp * 4 + reg;
                int n = n0 + fn * 16 + r16;
                if (i >= M || n >= N) continue;
                float v = acc[fm][fn][reg];
                if (EP == 4) {
                    v = prelu_f(v + bias[n], al) + res[(size_t)b * sRes + (size_t)i * N + n];
                } else if (EP == 5) {
                    float d2 = rvb[i] + rvb[n] - 2.f * v;
                    v = (i == n) ? 1.f : sqrtf(fmaxf(d2, 0.f));
                }
                Cb[(size_t)i * N + n] = v;
                if (EP == 5) Cb[(size_t)n * N + i] = v;   // mirror (same value; diag blocks benign)
            }
}

// =====================================================================
// Split-K reduce with epilogue.  One float4 per thread.
// EP: 0 none | 1 prelu(v+bias[n],*alpha) | 2 v*rv[i] | 3 relu(rv[i]*v+bias[n])
// =====================================================================
__global__ __launch_bounds__(256)
void k_reduce(const float* __restrict__ part, int nsplit, float* __restrict__ C, int sC,
              int M, int N, int EP, const float* __restrict__ bias,
              const float* __restrict__ alpha, const float* __restrict__ rv, int rvStride)
{
    int b = blockIdx.y;
    int MN = M * N;
    int flat = (blockIdx.x * 256 + threadIdx.x) * 4;
    if (flat >= MN) return;
    const float* p = part + (size_t)b * nsplit * MN + flat;
    float4 v = *(const float4*)p;
    for (int s = 1; s < nsplit; ++s) {
        float4 w = *(const float4*)(p + (size_t)s * MN);
        v.x += w.x; v.y += w.y; v.z += w.z; v.w += w.w;
    }
    float o[4] = {v.x, v.y, v.z, v.w};
    int i = flat / N, n = flat - i * N;     // N % 4 == 0: float4 never crosses a row
    if (EP == 1) {
        float al = *alpha;
#pragma unroll
        for (int j = 0; j < 4; ++j) o[j] = prelu_f(o[j] + bias[n + j], al);
    } else if (EP == 2) {
        float r = rv[(size_t)b * rvStride + i];
#pragma unroll
        for (int j = 0; j < 4; ++j) o[j] *= r;
    } else if (EP == 3) {
        float r = rv[(size_t)b * rvStride + i];
#pragma unroll
        for (int j = 0; j < 4; ++j) { float t = r * o[j] + bias[n + j]; o[j] = t > 0.f ? t : 0.f; }
    }
    float* co = C + (size_t)b * sC + flat;
    *(float4*)co = make_float4(o[0], o[1], o[2], o[3]);
}

// =====================================================================
// Row softmax over 512 cols + sq = sum(bf16(p)^2) — consistent with the
// bf16-rounded P the MFMA pdist kernel will consume.
// =====================================================================
__global__ __launch_bounds__(512)
void k_softmax_sq(const float* __restrict__ scores, float* __restrict__ P,
                  float* __restrict__ sq)
{
    int row = blockIdx.x;
    int t = threadIdx.x;
    int w = t >> 6, lane = t & 63;
    __shared__ float sm[8];

    float v = scores[(size_t)row * SS + t];
    float m = v;
    for (int off = 32; off; off >>= 1) m = fmaxf(m, __shfl_xor(m, off, 64));
    if (lane == 0) sm[w] = m;
    __syncthreads();
    m = sm[0];
#pragma unroll
    for (int i = 1; i < 8; ++i) m = fmaxf(m, sm[i]);
    __syncthreads();

    float e = expf(v - m);
    float s = e;
    for (int off = 32; off; off >>= 1) s += __shfl_xor(s, off, 64);
    if (lane == 0) sm[w] = s;
    __syncthreads();
    s = 0.f;
#pragma unroll
    for (int i = 0; i < 8; ++i) s += sm[i];
    __syncthreads();

    float p = e / s;
    P[(size_t)row * SS + t] = p;

    float pf = bf2f(f2bf(p));          // round like MFMA staging will
    float q = pf * pf;
    for (int off = 32; off; off >>= 1) q += __shfl_xor(q, off, 64);
    if (lane == 0) sm[w] = q;
    __syncthreads();
    if (t == 0) {
        float r = 0.f;
#pragma unroll
        for (int i = 0; i < 8; ++i) r += sm[i];
        sq[row] = r;
    }
}

// =====================================================================
// dh[row] = rsqrt(rowsum(Bm))
// =====================================================================
__global__ __launch_bounds__(512)
void k_dh(const float* __restrict__ Bm, float* __restrict__ dh)
{
    int row = blockIdx.x;
    int t = threadIdx.x;
    int w = t >> 6, lane = t & 63;
    __shared__ float sm[8];
    float v = Bm[(size_t)row * SS + t];
    for (int off = 32; off; off >>= 1) v += __shfl_xor(v, off, 64);
    if (lane == 0) sm[w] = v;
    __syncthreads();
    if (t == 0) {
        float r = 0.f;
#pragma unroll
        for (int i = 0; i < 8; ++i) r += sm[i];
        dh[row] = rsqrtf(r);
    }
}

// =====================================================================
// Logits + softmax over n.  block = (b, 8 s-rows), 256 thr.
// div written in (b, n, s) layout.
// =====================================================================
__global__ __launch_bounds__(256)
void k_div8(const float* __restrict__ h1, const float* __restrict__ h2,
            const float* __restrict__ b4a, const float* __restrict__ a4ap,
            const float* __restrict__ W4b, const float* __restrict__ b4bp,
            const float* __restrict__ a4bp, float* __restrict__ divT)
{
    int b = blockIdx.y;
    int s0 = blockIdx.x * 8;
    int tid = threadIdx.x;

    __shared__ float sh[8][104];
    __shared__ float sw[100];
    __shared__ float L[8][400];

    for (int idx = tid; idx < 800; idx += 256) {
        int s = idx / 100, d = idx - 100 * s;
        sh[s][d] = h2[((size_t)(b * SS + s0 + s)) * DD + d] + b4a[d];
    }
    if (tid < 100) sw[tid] = W4b[tid];
    __syncthreads();

    float a4a = *a4ap, a4b = *a4bp, b4b = *b4bp;

    for (int n = tid; n < NN; n += 256) {
        const float* h1r = &h1[((size_t)b * NN + n) * DD];
        float accs[8] = {0.f, 0.f, 0.f, 0.f, 0.f, 0.f, 0.f, 0.f};
        for (int j = 0; j < DD; j += 4) {
            float4 hv = *(const float4*)&h1r[j];
            float4 wv = *(const float4*)&sw[j];
#pragma unroll
            for (int s = 0; s < 8; ++s) {
                float4 cv = *(const float4*)&sh[s][j];
                float x0 = hv.x + cv.x; x0 = x0 > 0.f ? x0 : a4a * x0;
                float x1 = hv.y + cv.y; x1 = x1 > 0.f ? x1 : a4a * x1;
                float x2 = hv.z + cv.z; x2 = x2 > 0.f ? x2 : a4a * x2;
                float x3 = hv.w + cv.w; x3 = x3 > 0.f ? x3 : a4a * x3;
                accs[s] += x0 * wv.x + x1 * wv.y + x2 * wv.z + x3 * wv.w;
            }
        }
#pragma unroll
        for (int s = 0; s < 8; ++s) L[s][n] = prelu_f(accs[s] + b4b, a4b);
    }
    __syncthreads();

    int w = tid >> 6, lane = tid & 63;
    for (int si = w; si < 8; si += 4) {
        float m = -INFINITY;
        for (int n = lane; n < NN; n += 64) m = fmaxf(m, L[si][n]);
        for (int off = 32; off; off >>= 1) m = fmaxf(m, __shfl_xor(m, off, 64));
        float ss = 0.f;
        for (int n = lane; n < NN; n += 64) {
            float e = expf(L[si][n] - m);
            L[si][n] = e;
            ss += e;
        }
        for (int off = 32; off; off >>= 1) ss += __shfl_xor(ss, off, 64);
        float inv = 1.f / ss;
        for (int n = lane; n < NN; n += 64)
            divT[((size_t)b * NN + n) * SS + s0 + si] = L[si][n] * inv;
    }
}

extern "C" void kernel_launch(void* const* d_in, const int* in_sizes, int n_in,
                              void* d_out, int out_size, void* d_ws, size_t ws_size,
                              hipStream_t stream) {
    const float* x   = (const float*)d_in[0];
    const float* G   = (const float*)d_in[1];
    const float* Am  = (const float*)d_in[2];
    const float* Wgf = (const float*)d_in[3];
    const float* bgf = (const float*)d_in[4];
    const float* agf = (const float*)d_in[5];
    const float* Wg  = (const float*)d_in[6];
    const float* bg  = (const float*)d_in[7];
    const float* W4a = (const float*)d_in[8];
    const float* b4a = (const float*)d_in[9];
    const float* a4a = (const float*)d_in[10];
    const float* W4b = (const float*)d_in[11];
    const float* b4b = (const float*)d_in[12];
    const float* a4b = (const float*)d_in[13];
    const float* W5  = (const float*)d_in[14];
    const float* b5  = (const float*)d_in[15];
    const float* a5  = (const float*)d_in[16];
    float* out = (float*)d_out;

    float* ws  = (float*)d_ws;
    float* G1  = ws;                 // 51200
    float* Ax  = ws + 51200;         // 204800
    float* P   = ws + 256000;        // 1048576
    float* BmS = ws + 1304576;       // 1048576 (scores, then Bm)
    float* sq  = ws + 2353152;       // 2048
    float* dh  = ws + 2355200;       // 2048
    float* PW  = ws + 2357248;       // 204800
    float* T1s = ws + 2562048;       // 204800
    float* gx  = ws + 2766848;       // 204800
    float* h1  = ws + 2971648;       // 160000
    float* h2  = ws + 3131648;       // 204800
    float* tmp = ws + 3336448;       // 160000  (end 3496448)
    float* divT  = P;                // P dead after step 7; written step 12
    float* part  = h1;               // partials steps 1,2,7 (h1..tmp region, 524800 floats)
    float* partP = P;                // partials steps 8,9 (P dead after 7; 819200 <= 1048576)
    float* partB = BmS;              // partials step 13 (Bm dead after 9)

    // 1. G1 = prelu(G @ Wgf^T + bgf)          M=512 N=100 K=400, split-K 2
    mmfa<<<dim3(16, 4, 2), 64, 0, stream>>>(G, NN, 0, Wgf, NN, 0, 1,
        part, 0, SS, DD, NN, 2, 224, 0, nullptr, nullptr, nullptr, 0, nullptr, 0);
    k_reduce<<<dim3(50, 1), 256, 0, stream>>>(part, 2, G1, SS * DD, SS, DD, 1, bgf, agf, nullptr, 0);
    // 2. Ax[b] = Amat @ x[b]                  M=512 N=100 K=400, split-K 2
    mmfa<<<dim3(16, 4, 2 * BB), 64, 0, stream>>>(Am, NN, 0, x, DD, NN * DD, 0,
        part, 0, SS, DD, NN, 2, 224, 0, nullptr, nullptr, nullptr, 0, nullptr, 0);
    k_reduce<<<dim3(50, BB), 256, 0, stream>>>(part, 2, Ax, SS * DD, SS, DD, 0, nullptr, nullptr, nullptr, 0);
    // 3. scores[b] = G1 @ Ax[b]^T             M=512 N=512 K=100
    mmfa<<<dim3(16, 16, BB), 64, 0, stream>>>(G1, DD, 0, Ax, DD, SS * DD, 1,
        BmS, SS * SS, SS, SS, DD, 1, DD, 0, nullptr, nullptr, nullptr, 0, nullptr, 0);
    // 4. P = softmax(scores), sq = sum(bf16(P)^2)
    k_softmax_sq<<<BB * SS, 512, 0, stream>>>(BmS, P, sq);
    // 5. Bm = pdist(P @ P^T), triangular + mirror   M=N=K=512
    mmfa<<<dim3(16, 16, BB), 64, 0, stream>>>(P, SS, SS * SS, P, SS, SS * SS, 1,
        BmS, SS * SS, SS, SS, SS, 1, SS, 5, nullptr, nullptr, sq, SS, nullptr, 0);
    // 6. dh = rsqrt(rowsum(Bm))
    k_dh<<<BB * SS, 512, 0, stream>>>(BmS, dh);
    // 7. PW[b] = P[b] @ Wg^T                  M=512 N=100 K=512, split-K 2
    mmfa<<<dim3(16, 4, 2 * BB), 64, 0, stream>>>(P, SS, SS * SS, Wg, SS, 0, 1,
        part, 0, SS, DD, SS, 2, 256, 0, nullptr, nullptr, nullptr, 0, nullptr, 0);
    k_reduce<<<dim3(50, BB), 256, 0, stream>>>(part, 2, PW, SS * DD, SS, DD, 0, nullptr, nullptr, nullptr, 0);
    // 8. T1s[b] = diag(dh) @ (Bm @ PW)        split-K 4
    mmfa<<<dim3(16, 4, 4 * BB), 64, 0, stream>>>(BmS, SS, SS * SS, PW, DD, SS * DD, 0,
        partP, 0, SS, DD, SS, 4, 128, 0, nullptr, nullptr, nullptr, 0, nullptr, 0);
    k_reduce<<<dim3(50, BB), 256, 0, stream>>>(partP, 4, T1s, SS * DD, SS, DD, 2, nullptr, nullptr, dh, SS);
    // 9. gx[b] = relu(diag(dh) @ (Bm @ T1s) + bg)   split-K 4
    mmfa<<<dim3(16, 4, 4 * BB), 64, 0, stream>>>(BmS, SS, SS * SS, T1s, DD, SS * DD, 0,
        partP, 0, SS, DD, SS, 4, 128, 0, nullptr, nullptr, nullptr, 0, nullptr, 0);
    k_reduce<<<dim3(50, BB), 256, 0, stream>>>(partP, 4, gx, SS * DD, SS, DD, 3, bg, nullptr, dh, SS);
    // 10. h1[b] = x[b] @ W4a[:, :100]^T       M=400 N=100 K=100
    mmfa<<<dim3(13, 4, BB), 64, 0, stream>>>(x, DD, NN * DD, W4a, 2 * DD, 0, 1,
        h1, NN * DD, NN, DD, DD, 1, DD, 0, nullptr, nullptr, nullptr, 0, nullptr, 0);
    // 11. h2[b] = gx[b] @ W4a[:, 100:]^T      M=512 N=100 K=100
    mmfa<<<dim3(16, 4, BB), 64, 0, stream>>>(gx, DD, SS * DD, W4a + DD, 2 * DD, 0, 1,
        h2, SS * DD, SS, DD, DD, 1, DD, 0, nullptr, nullptr, nullptr, 0, nullptr, 0);
    // 12. div (b,n,s) = softmax_n(logits)
    k_div8<<<dim3(SS / 8, BB), 256, 0, stream>>>(h1, h2, b4a, a4a, W4b, b4b, a4b, divT);
    // 13. tmp[b] = div[b] @ gx[b]             M=400 N=100 K=512, split-K 4
    mmfa<<<dim3(13, 4, 4 * BB), 64, 0, stream>>>(divT, SS, NN * SS, gx, DD, SS * DD, 0,
        partB, 0, NN, DD, SS, 4, 128, 0, nullptr, nullptr, nullptr, 0, nullptr, 0);
    k_reduce<<<dim3(40, BB), 256, 0, stream>>>(partB, 4, tmp, NN * DD, NN, DD, 0, nullptr, nullptr, nullptr, 0);
    // 14. out = prelu(tmp @ W5^T + b5, a5) + x   M=400 N=100 K=100
    mmfa<<<dim3(13, 4, BB), 64, 0, stream>>>(tmp, DD, NN * DD, W5, DD, 0, 1,
        out, NN * DD, NN, DD, DD, 1, DD, 4, b5, a5, nullptr, 0, x, NN * DD);
}

// Round 9
// 293.374 us; speedup vs baseline: 1.9118x; 1.1695x over previous
//
#include <hip/hip_runtime.h>
#include <hip/hip_bf16.h>

#define BB 4
#define NN 400
#define DD 100
#define SS 512

typedef __attribute__((ext_vector_type(8))) short bf16x8;
typedef __attribute__((ext_vector_type(4))) float f32x4;

__device__ __forceinline__ float prelu_f(float v, float a) { return v >= 0.f ? v : a * v; }

__device__ __forceinline__ unsigned short f2bf(float x) {
    union { __hip_bfloat16 h; unsigned short u; } c;
    c.h = __float2bfloat16(x);   // RNE
    return c.u;
}
__device__ __forceinline__ float bf2f(unsigned short u) {
    return __uint_as_float(((unsigned)u) << 16);
}

__device__ __forceinline__ bf16x8 ldfrag(const unsigned short* rowp, int grp) {
    ushort4 lo = *(const ushort4*)(rowp + grp * 4);
    ushort4 hi = *(const ushort4*)(rowp + grp * 4 + 16);
    bf16x8 r = {(short)lo.x, (short)lo.y, (short)lo.z, (short)lo.w,
                (short)hi.x, (short)hi.y, (short)hi.z, (short)hi.w};
    return r;
}

#define LPAD 136   // row stride (ushorts): 68 dwords == 4 mod 32 -> <=2-way on frag reads

// =====================================================================
// MFMA bf16 GEMM, 256 thr (4 waves 2x2), block tile 64x64, K-step 128.
// Per wave: 32x32 output (2x2 frags of 16x16x32 bf16 MFMA).
// fp32 inputs converted RNE->bf16 at LDS staging.
// transB=1: B row-major [n][k] (ldb = k-stride); transB=0: B [k][n].
// nsplit>1: raw partials to C[(b*nsplit+split)*M*N]; k_reduce applies EP.
// nsplit==1: EP 0 none | 4 prelu(v+bias[n],*alpha)+res | 5 pdist
// (triangular: blocks i0>n0 return; mirror writes fill lower half).
// =====================================================================
__global__ __launch_bounds__(256)
void mmfa(const float* __restrict__ A, int lda, int sA,
          const float* __restrict__ B, int ldb, int sB, int transB,
          float* __restrict__ C, int sC, int M, int N, int K,
          int nsplit, int kchunk, int EP,
          const float* __restrict__ bias, const float* __restrict__ alpha,
          const float* __restrict__ rv, int rvStride,
          const float* __restrict__ res, int sRes)
{
    int zz = blockIdx.z;
    int b = zz / nsplit, split = zz - b * nsplit;
    int kbeg = split * kchunk, kend = min(K, kbeg + kchunk);
    int i0 = blockIdx.x * 64, n0 = blockIdx.y * 64;
    if (EP == 5 && i0 > n0) return;          // symmetric: lower mirrored

    const float* Ab = A + (size_t)b * sA;
    const float* Bb = B + (size_t)b * sB;
    int tid = threadIdx.x;
    int lane = tid & 63, wave = tid >> 6;
    int r16 = lane & 15, grp = (lane >> 4) & 3;
    int wr = wave >> 1, wc = wave & 1;       // 2x2 wave grid

    __shared__ unsigned short sa[64][LPAD];  // [m][k] bf16
    __shared__ unsigned short sb[64][LPAD];  // [n][k] bf16

    f32x4 acc[2][2];
#pragma unroll
    for (int fm = 0; fm < 2; ++fm)
#pragma unroll
        for (int fn = 0; fn < 2; ++fn)
            acc[fm][fn] = (f32x4){0.f, 0.f, 0.f, 0.f};

    for (int kt = kbeg; kt < kend; kt += 128) {
        // ---- stage A: 64 rows x 128 k, fp32 -> bf16
#pragma unroll
        for (int it = 0; it < 8; ++it) {
            int idx = tid + it * 256;        // 0..2047
            int row = idx >> 5;              // 0..63
            int kq = (idx & 31) * 4;         // 0..124
            float4 v = make_float4(0.f, 0.f, 0.f, 0.f);
            if (i0 + row < M && kt + kq + 4 <= kend)
                v = *(const float4*)&Ab[(size_t)(i0 + row) * lda + kt + kq];
            ushort4 u;
            u.x = f2bf(v.x); u.y = f2bf(v.y); u.z = f2bf(v.z); u.w = f2bf(v.w);
            *(ushort4*)&sa[row][kq] = u;
        }
        // ---- stage B
        if (transB) {
#pragma unroll
            for (int it = 0; it < 8; ++it) {
                int idx = tid + it * 256;
                int row = idx >> 5;          // n-local
                int kq = (idx & 31) * 4;
                float4 v = make_float4(0.f, 0.f, 0.f, 0.f);
                if (n0 + row < N && kt + kq + 4 <= kend)
                    v = *(const float4*)&Bb[(size_t)(n0 + row) * ldb + kt + kq];
                ushort4 u;
                u.x = f2bf(v.x); u.y = f2bf(v.y); u.z = f2bf(v.z); u.w = f2bf(v.w);
                *(ushort4*)&sb[row][kq] = u;
            }
        } else {
#pragma unroll
            for (int it = 0; it < 8; ++it) {
                int idx = tid + it * 256;
                int kk = idx >> 4;           // 0..127
                int nq = (idx & 15) * 4;     // 0..60
                float4 v = make_float4(0.f, 0.f, 0.f, 0.f);
                if (kt + kk < kend && n0 + nq + 4 <= N)
                    v = *(const float4*)&Bb[(size_t)(kt + kk) * ldb + n0 + nq];
                sb[nq + 0][kk] = f2bf(v.x);
                sb[nq + 1][kk] = f2bf(v.y);
                sb[nq + 2][kk] = f2bf(v.z);
                sb[nq + 3][kk] = f2bf(v.w);
            }
        }
        __syncthreads();

#pragma unroll
        for (int ks = 0; ks < 4; ++ks) {     // 4 x K=32 sub-windows
            bf16x8 a0 = ldfrag(&sa[wr * 32 + r16][ks * 32], grp);
            bf16x8 a1 = ldfrag(&sa[wr * 32 + 16 + r16][ks * 32], grp);
            bf16x8 b0 = ldfrag(&sb[wc * 32 + r16][ks * 32], grp);
            bf16x8 b1 = ldfrag(&sb[wc * 32 + 16 + r16][ks * 32], grp);
            acc[0][0] = __builtin_amdgcn_mfma_f32_16x16x32_bf16(a0, b0, acc[0][0], 0, 0, 0);
            acc[0][1] = __builtin_amdgcn_mfma_f32_16x16x32_bf16(a0, b1, acc[0][1], 0, 0, 0);
            acc[1][0] = __builtin_amdgcn_mfma_f32_16x16x32_bf16(a1, b0, acc[1][0], 0, 0, 0);
            acc[1][1] = __builtin_amdgcn_mfma_f32_16x16x32_bf16(a1, b1, acc[1][1], 0, 0, 0);
        }
        __syncthreads();
    }

    // ---- store: i = i0 + wr*32 + fm*16 + grp*4 + reg, n = n0 + wc*32 + fn*16 + r16
    if (nsplit > 1) {
        float* Pp = C + (size_t)(b * nsplit + split) * M * N;
#pragma unroll
        for (int fm = 0; fm < 2; ++fm)
#pragma unroll
            for (int fn = 0; fn < 2; ++fn)
#pragma unroll
                for (int reg = 0; reg < 4; ++reg) {
                    int i = i0 + wr * 32 + fm * 16 + grp * 4 + reg;
                    int n = n0 + wc * 32 + fn * 16 + r16;
                    if (i < M && n < N) Pp[(size_t)i * N + n] = acc[fm][fn][reg];
                }
        return;
    }

    float al = alpha ? *alpha : 0.f;
    const float* rvb = rv ? rv + (size_t)b * rvStride : nullptr;
    float* Cb = C + (size_t)b * sC;
#pragma unroll
    for (int fm = 0; fm < 2; ++fm)
#pragma unroll
        for (int fn = 0; fn < 2; ++fn)
#pragma unroll
            for (int reg = 0; reg < 4; ++reg) {
                int i = i0 + wr * 32 + fm * 16 + grp * 4 + reg;
                int n = n0 + wc * 32 + fn * 16 + r16;
                if (i >= M || n >= N) continue;
                float v = acc[fm][fn][reg];
                if (EP == 4) {
                    v = prelu_f(v + bias[n], al) + res[(size_t)b * sRes + (size_t)i * N + n];
                } else if (EP == 5) {
                    float d2 = rvb[i] + rvb[n] - 2.f * v;
                    v = (i == n) ? 1.f : sqrtf(fmaxf(d2, 0.f));
                }
                Cb[(size_t)i * N + n] = v;
                if (EP == 5) Cb[(size_t)n * N + i] = v;   // mirror (same value; diag benign)
            }
}

// =====================================================================
// Split-K reduce with epilogue.  One float4 per thread.
// EP: 0 none | 1 prelu(v+bias[n],*alpha) | 2 v*rv[i] | 3 relu(rv[i]*v+bias[n])
// =====================================================================
__global__ __launch_bounds__(256)
void k_reduce(const float* __restrict__ part, int nsplit, float* __restrict__ C, int sC,
              int M, int N, int EP, const float* __restrict__ bias,
              const float* __restrict__ alpha, const float* __restrict__ rv, int rvStride)
{
    int b = blockIdx.y;
    int MN = M * N;
    int flat = (blockIdx.x * 256 + threadIdx.x) * 4;
    if (flat >= MN) return;
    const float* p = part + (size_t)b * nsplit * MN + flat;
    float4 v = *(const float4*)p;
    for (int s = 1; s < nsplit; ++s) {
        float4 w = *(const float4*)(p + (size_t)s * MN);
        v.x += w.x; v.y += w.y; v.z += w.z; v.w += w.w;
    }
    float o[4] = {v.x, v.y, v.z, v.w};
    int i = flat / N, n = flat - i * N;     // N % 4 == 0: float4 never crosses a row
    if (EP == 1) {
        float al = *alpha;
#pragma unroll
        for (int j = 0; j < 4; ++j) o[j] = prelu_f(o[j] + bias[n + j], al);
    } else if (EP == 2) {
        float r = rv[(size_t)b * rvStride + i];
#pragma unroll
        for (int j = 0; j < 4; ++j) o[j] *= r;
    } else if (EP == 3) {
        float r = rv[(size_t)b * rvStride + i];
#pragma unroll
        for (int j = 0; j < 4; ++j) { float t = r * o[j] + bias[n + j]; o[j] = t > 0.f ? t : 0.f; }
    }
    float* co = C + (size_t)b * sC + flat;
    *(float4*)co = make_float4(o[0], o[1], o[2], o[3]);
}

// =====================================================================
// Row softmax over 512 cols + sq = sum(bf16(p)^2) — consistent with the
// bf16-rounded P the MFMA pdist kernel consumes.
// =====================================================================
__global__ __launch_bounds__(512)
void k_softmax_sq(const float* __restrict__ scores, float* __restrict__ P,
                  float* __restrict__ sq)
{
    int row = blockIdx.x;
    int t = threadIdx.x;
    int w = t >> 6, lane = t & 63;
    __shared__ float sm[8];

    float v = scores[(size_t)row * SS + t];
    float m = v;
    for (int off = 32; off; off >>= 1) m = fmaxf(m, __shfl_xor(m, off, 64));
    if (lane == 0) sm[w] = m;
    __syncthreads();
    m = sm[0];
#pragma unroll
    for (int i = 1; i < 8; ++i) m = fmaxf(m, sm[i]);
    __syncthreads();

    float e = expf(v - m);
    float s = e;
    for (int off = 32; off; off >>= 1) s += __shfl_xor(s, off, 64);
    if (lane == 0) sm[w] = s;
    __syncthreads();
    s = 0.f;
#pragma unroll
    for (int i = 0; i < 8; ++i) s += sm[i];
    __syncthreads();

    float p = e / s;
    P[(size_t)row * SS + t] = p;

    float pf = bf2f(f2bf(p));          // round like MFMA staging will
    float q = pf * pf;
    for (int off = 32; off; off >>= 1) q += __shfl_xor(q, off, 64);
    if (lane == 0) sm[w] = q;
    __syncthreads();
    if (t == 0) {
        float r = 0.f;
#pragma unroll
        for (int i = 0; i < 8; ++i) r += sm[i];
        sq[row] = r;
    }
}

// =====================================================================
// dh[row] = rsqrt(rowsum(Bm))
// =====================================================================
__global__ __launch_bounds__(512)
void k_dh(const float* __restrict__ Bm, float* __restrict__ dh)
{
    int row = blockIdx.x;
    int t = threadIdx.x;
    int w = t >> 6, lane = t & 63;
    __shared__ float sm[8];
    float v = Bm[(size_t)row * SS + t];
    for (int off = 32; off; off >>= 1) v += __shfl_xor(v, off, 64);
    if (lane == 0) sm[w] = v;
    __syncthreads();
    if (t == 0) {
        float r = 0.f;
#pragma unroll
        for (int i = 0; i < 8; ++i) r += sm[i];
        dh[row] = rsqrtf(r);
    }
}

// =====================================================================
// Logits + softmax over n.  block = (b, 8 s-rows), 256 thr.
// div written in (b, n, s) layout.
// =====================================================================
__global__ __launch_bounds__(256)
void k_div8(const float* __restrict__ h1, const float* __restrict__ h2,
            const float* __restrict__ b4a, const float* __restrict__ a4ap,
            const float* __restrict__ W4b, const float* __restrict__ b4bp,
            const float* __restrict__ a4bp, float* __restrict__ divT)
{
    int b = blockIdx.y;
    int s0 = blockIdx.x * 8;
    int tid = threadIdx.x;

    __shared__ float sh[8][104];
    __shared__ float sw[100];
    __shared__ float L[8][400];

    for (int idx = tid; idx < 800; idx += 256) {
        int s = idx / 100, d = idx - 100 * s;
        sh[s][d] = h2[((size_t)(b * SS + s0 + s)) * DD + d] + b4a[d];
    }
    if (tid < 100) sw[tid] = W4b[tid];
    __syncthreads();

    float a4a = *a4ap, a4b = *a4bp, b4b = *b4bp;

    for (int n = tid; n < NN; n += 256) {
        const float* h1r = &h1[((size_t)b * NN + n) * DD];
        float accs[8] = {0.f, 0.f, 0.f, 0.f, 0.f, 0.f, 0.f, 0.f};
        for (int j = 0; j < DD; j += 4) {
            float4 hv = *(const float4*)&h1r[j];
            float4 wv = *(const float4*)&sw[j];
#pragma unroll
            for (int s = 0; s < 8; ++s) {
                float4 cv = *(const float4*)&sh[s][j];
                float x0 = hv.x + cv.x; x0 = x0 > 0.f ? x0 : a4a * x0;
                float x1 = hv.y + cv.y; x1 = x1 > 0.f ? x1 : a4a * x1;
                float x2 = hv.z + cv.z; x2 = x2 > 0.f ? x2 : a4a * x2;
                float x3 = hv.w + cv.w; x3 = x3 > 0.f ? x3 : a4a * x3;
                accs[s] += x0 * wv.x + x1 * wv.y + x2 * wv.z + x3 * wv.w;
            }
        }
#pragma unroll
        for (int s = 0; s < 8; ++s) L[s][n] = prelu_f(accs[s] + b4b, a4b);
    }
    __syncthreads();

    int w = tid >> 6, lane = tid & 63;
    for (int si = w; si < 8; si += 4) {
        float m = -INFINITY;
        for (int n = lane; n < NN; n += 64) m = fmaxf(m, L[si][n]);
        for (int off = 32; off; off >>= 1) m = fmaxf(m, __shfl_xor(m, off, 64));
        float ss = 0.f;
        for (int n = lane; n < NN; n += 64) {
            float e = expf(L[si][n] - m);
            L[si][n] = e;
            ss += e;
        }
        for (int off = 32; off; off >>= 1) ss += __shfl_xor(ss, off, 64);
        float inv = 1.f / ss;
        for (int n = lane; n < NN; n += 64)
            divT[((size_t)b * NN + n) * SS + s0 + si] = L[si][n] * inv;
    }
}

extern "C" void kernel_launch(void* const* d_in, const int* in_sizes, int n_in,
                              void* d_out, int out_size, void* d_ws, size_t ws_size,
                              hipStream_t stream) {
    const float* x   = (const float*)d_in[0];
    const float* G   = (const float*)d_in[1];
    const float* Am  = (const float*)d_in[2];
    const float* Wgf = (const float*)d_in[3];
    const float* bgf = (const float*)d_in[4];
    const float* agf = (const float*)d_in[5];
    const float* Wg  = (const float*)d_in[6];
    const float* bg  = (const float*)d_in[7];
    const float* W4a = (const float*)d_in[8];
    const float* b4a = (const float*)d_in[9];
    const float* a4a = (const float*)d_in[10];
    const float* W4b = (const float*)d_in[11];
    const float* b4b = (const float*)d_in[12];
    const float* a4b = (const float*)d_in[13];
    const float* W5  = (const float*)d_in[14];
    const float* b5  = (const float*)d_in[15];
    const float* a5  = (const float*)d_in[16];
    float* out = (float*)d_out;

    float* ws  = (float*)d_ws;
    float* G1  = ws;                 // 51200
    float* Ax  = ws + 51200;         // 204800
    float* P   = ws + 256000;        // 1048576
    float* BmS = ws + 1304576;       // 1048576 (scores, then Bm)
    float* sq  = ws + 2353152;       // 2048
    float* dh  = ws + 2355200;       // 2048
    float* PW  = ws + 2357248;       // 204800
    float* T1s = ws + 2562048;       // 204800
    float* gx  = ws + 2766848;       // 204800
    float* h1  = ws + 2971648;       // 160000
    float* h2  = ws + 3131648;       // 204800
    float* tmp = ws + 3336448;       // 160000  (end 3496448)
    float* divT  = P;                // P dead after step 7; written step 12
    float* part  = h1;               // partials steps 1,2,7 (h1..tmp region, 524800 floats)
    float* partP = P;                // partials steps 8,9 (P dead after 7)
    float* partB = BmS;              // partials step 13 (Bm dead after 9)

    // 1. G1 = prelu(G @ Wgf^T + bgf)          M=512 N=100 K=400, split-K 2
    mmfa<<<dim3(8, 2, 2), 256, 0, stream>>>(G, NN, 0, Wgf, NN, 0, 1,
        part, 0, SS, DD, NN, 2, 200, 0, nullptr, nullptr, nullptr, 0, nullptr, 0);
    k_reduce<<<dim3(50, 1), 256, 0, stream>>>(part, 2, G1, SS * DD, SS, DD, 1, bgf, agf, nullptr, 0);
    // 2. Ax[b] = Amat @ x[b]                  M=512 N=100 K=400, split-K 2
    mmfa<<<dim3(8, 2, 2 * BB), 256, 0, stream>>>(Am, NN, 0, x, DD, NN * DD, 0,
        part, 0, SS, DD, NN, 2, 200, 0, nullptr, nullptr, nullptr, 0, nullptr, 0);
    k_reduce<<<dim3(50, BB), 256, 0, stream>>>(part, 2, Ax, SS * DD, SS, DD, 0, nullptr, nullptr, nullptr, 0);
    // 3. scores[b] = G1 @ Ax[b]^T             M=512 N=512 K=100
    mmfa<<<dim3(8, 8, BB), 256, 0, stream>>>(G1, DD, 0, Ax, DD, SS * DD, 1,
        BmS, SS * SS, SS, SS, DD, 1, DD, 0, nullptr, nullptr, nullptr, 0, nullptr, 0);
    // 4. P = softmax(scores), sq = sum(bf16(P)^2)
    k_softmax_sq<<<BB * SS, 512, 0, stream>>>(BmS, P, sq);
    // 5. Bm = pdist(P @ P^T), triangular + mirror   M=N=K=512
    mmfa<<<dim3(8, 8, BB), 256, 0, stream>>>(P, SS, SS * SS, P, SS, SS * SS, 1,
        BmS, SS * SS, SS, SS, SS, 1, SS, 5, nullptr, nullptr, sq, SS, nullptr, 0);
    // 6. dh = rsqrt(rowsum(Bm))
    k_dh<<<BB * SS, 512, 0, stream>>>(BmS, dh);
    // 7. PW[b] = P[b] @ Wg^T                  M=512 N=100 K=512, split-K 2
    mmfa<<<dim3(8, 2, 2 * BB), 256, 0, stream>>>(P, SS, SS * SS, Wg, SS, 0, 1,
        part, 0, SS, DD, SS, 2, 256, 0, nullptr, nullptr, nullptr, 0, nullptr, 0);
    k_reduce<<<dim3(50, BB), 256, 0, stream>>>(part, 2, PW, SS * DD, SS, DD, 0, nullptr, nullptr, nullptr, 0);
    // 8. T1s[b] = diag(dh) @ (Bm @ PW)        split-K 2
    mmfa<<<dim3(8, 2, 2 * BB), 256, 0, stream>>>(BmS, SS, SS * SS, PW, DD, SS * DD, 0,
        partP, 0, SS, DD, SS, 2, 256, 0, nullptr, nullptr, nullptr, 0, nullptr, 0);
    k_reduce<<<dim3(50, BB), 256, 0, stream>>>(partP, 2, T1s, SS * DD, SS, DD, 2, nullptr, nullptr, dh, SS);
    // 9. gx[b] = relu(diag(dh) @ (Bm @ T1s) + bg)   split-K 2
    mmfa<<<dim3(8, 2, 2 * BB), 256, 0, stream>>>(BmS, SS, SS * SS, T1s, DD, SS * DD, 0,
        partP, 0, SS, DD, SS, 2, 256, 0, nullptr, nullptr, nullptr, 0, nullptr, 0);
    k_reduce<<<dim3(50, BB), 256, 0, stream>>>(partP, 2, gx, SS * DD, SS, DD, 3, bg, nullptr, dh, SS);
    // 10. h1[b] = x[b] @ W4a[:, :100]^T       M=400 N=100 K=100
    mmfa<<<dim3(7, 2, BB), 256, 0, stream>>>(x, DD, NN * DD, W4a, 2 * DD, 0, 1,
        h1, NN * DD, NN, DD, DD, 1, DD, 0, nullptr, nullptr, nullptr, 0, nullptr, 0);
    // 11. h2[b] = gx[b] @ W4a[:, 100:]^T      M=512 N=100 K=100
    mmfa<<<dim3(8, 2, BB), 256, 0, stream>>>(gx, DD, SS * DD, W4a + DD, 2 * DD, 0, 1,
        h2, SS * DD, SS, DD, DD, 1, DD, 0, nullptr, nullptr, nullptr, 0, nullptr, 0);
    // 12. div (b,n,s) = softmax_n(logits)
    k_div8<<<dim3(SS / 8, BB), 256, 0, stream>>>(h1, h2, b4a, a4a, W4b, b4b, a4b, divT);
    // 13. tmp[b] = div[b] @ gx[b]             M=400 N=100 K=512, split-K 2
    mmfa<<<dim3(7, 2, 2 * BB), 256, 0, stream>>>(divT, SS, NN * SS, gx, DD, SS * DD, 0,
        partB, 0, NN, DD, SS, 2, 256, 0, nullptr, nullptr, nullptr, 0, nullptr, 0);
    k_reduce<<<dim3(40, BB), 256, 0, stream>>>(partB, 2, tmp, NN * DD, NN, DD, 0, nullptr, nullptr, nullptr, 0);
    // 14. out = prelu(tmp @ W5^T + b5, a5) + x   M=400 N=100 K=100
    mmfa<<<dim3(7, 2, BB), 256, 0, stream>>>(tmp, DD, NN * DD, W5, DD, 0, 1,
        out, NN * DD, NN, DD, DD, 1, DD, 4, b5, a5, nullptr, 0, x, NN * DD);
}